// Round 2
// baseline (74636.176 us; speedup 1.0000x reference)
//
#include <hip/hip_runtime.h>
#include <hip/hip_bf16.h>

#define N 4096
#define L 4096

// ---------- helpers ----------
__device__ __forceinline__ float bf2f(unsigned u_low16) {
    union { unsigned u; float f; } cv; cv.u = u_low16 << 16; return cv.f;
}
__device__ __forceinline__ unsigned short f2bf(float f) {
    union { float f; unsigned u; } cv; cv.f = f;
    unsigned r = cv.u + 0x7fffu + ((cv.u >> 16) & 1u);
    return (unsigned short)(r >> 16);
}

// ---------- init: zero d_out, set state buffers ----------
__global__ __launch_bounds__(256) void init_kernel(const float* __restrict__ sd,
                                                   float* __restrict__ bufs,
                                                   float* __restrict__ out) {
    int tid = blockIdx.x * 256 + threadIdx.x;      // grid 64 blocks -> 16384 threads
    if (tid < L * 4) out[tid] = 0.0f;
    if (tid < N) bufs[tid] = sd[tid];              // buf0 = initial state
    else if (tid < 3 * N) bufs[tid] = 0.0f;        // buf1, buf2 = 0
}

// ---------- robust symbol decode: handles int32 OR int64 device layout ----------
// If the harness kept jnp.int64, the int32 view is [v0,0,v1,0,...] -> all odd
// words zero. Genuine int32 random 0/1 data has nonzero odd words w.p. ~1.
__global__ __launch_bounds__(256) void decode_seq_kernel(const int* __restrict__ seq32,
                                                         unsigned char* __restrict__ syms) {
    __shared__ int any_odd;
    if (threadIdx.x == 0) any_odd = 0;
    __syncthreads();
    int acc = 0;
    for (int i = threadIdx.x; i < L / 2; i += 256) acc |= seq32[2 * i + 1]; // odd idx < 4096
    if (acc) any_odd = 1;
    __syncthreads();
    const int is64 = (any_odd == 0);
    for (int t = threadIdx.x; t < L; t += 256) {
        int v = is64 ? seq32[2 * t] : seq32[t];
        syms[t] = (unsigned char)(v & 1);
    }
}

// ---------- softmax over T rows -> Tm[s][i][j] (fp32 or bf16) ----------
template <int FP32>
__global__ __launch_bounds__(256) void softmax_T_kernel(const float* __restrict__ T,
                                                        void* __restrict__ TmV) {
    int row = blockIdx.x;              // 0..8191 == i*2 + s
    int i = row >> 1, s = row & 1;
    const float* src = T + (size_t)row * N;
    size_t doff = ((size_t)s << 24) + ((size_t)i << 12);
    int tid = threadIdx.x;

    float vals[16];
    float mx = -1e30f;
#pragma unroll
    for (int k = 0; k < 16; k++) {
        vals[k] = src[tid + (k << 8)];
        mx = fmaxf(mx, vals[k]);
    }
#pragma unroll
    for (int o = 32; o > 0; o >>= 1) mx = fmaxf(mx, __shfl_xor(mx, o));
    __shared__ float redmax[4];
    __shared__ float redsum[4];
    int wid = tid >> 6;
    if ((tid & 63) == 0) redmax[wid] = mx;
    __syncthreads();
    mx = fmaxf(fmaxf(redmax[0], redmax[1]), fmaxf(redmax[2], redmax[3]));

    float sum = 0.0f;
#pragma unroll
    for (int k = 0; k < 16; k++) {
        vals[k] = __expf(vals[k] - mx);
        sum += vals[k];
    }
#pragma unroll
    for (int o = 32; o > 0; o >>= 1) sum += __shfl_xor(sum, o);
    if ((tid & 63) == 0) redsum[wid] = sum;
    __syncthreads();
    sum = redsum[0] + redsum[1] + redsum[2] + redsum[3];
    float inv = 1.0f / sum;
    if (FP32) {
        float* dst = (float*)TmV + doff;
#pragma unroll
        for (int k = 0; k < 16; k++) dst[tid + (k << 8)] = vals[k] * inv;
    } else {
        unsigned short* dst = (unsigned short*)TmV + doff;
#pragma unroll
        for (int k = 0; k < 16; k++) dst[tid + (k << 8)] = f2bf(vals[k] * inv);
    }
}

// ---------- softmax over O rows (4 wide) -> fp32 Om[s][i][c] ----------
__global__ __launch_bounds__(256) void softmax_O_kernel(const float* __restrict__ O,
                                                        float* __restrict__ Om) {
    int r = blockIdx.x * 256 + threadIdx.x;        // 0..8191 == i*2 + s
    if (r < 2 * N) {
        float4 x = *(const float4*)(O + (size_t)r * 4);
        float mx = fmaxf(fmaxf(x.x, x.y), fmaxf(x.z, x.w));
        float e0 = __expf(x.x - mx), e1 = __expf(x.y - mx);
        float e2 = __expf(x.z - mx), e3 = __expf(x.w - mx);
        float inv = 1.0f / (e0 + e1 + e2 + e3);
        int i = r >> 1, s = r & 1;
        *(float4*)(Om + (size_t)s * (N * 4) + (size_t)i * 4) =
            make_float4(e0 * inv, e1 * inv, e2 * inv, e3 * inv);
    }
}

// ---------- one scan step ----------
// grid = 256 blocks: blockIdx & 3 = j-block (1024 cols), blockIdx >> 2 = i-chunk (64 rows)
// reads vr = bufs[t%3], atomically accumulates vw = bufs[(t+1)%3], zeros vz = bufs[(t+2)%3]
// jb==0 blocks also accumulate out[t][0..3] = vr . Om[s]
template <int FP32>
__global__ __launch_bounds__(256) void step_kernel(const void* __restrict__ TmV,
                                                   const float* __restrict__ Om,
                                                   const unsigned char* __restrict__ syms,
                                                   float* __restrict__ bufs,
                                                   float* __restrict__ out,
                                                   int t) {
    const int s = syms[t];
    const float* vr = bufs + (size_t)(t % 3) * N;
    float* vw = bufs + (size_t)((t + 1) % 3) * N;
    float* vz = bufs + (size_t)((t + 2) % 3) * N;

    int tid = threadIdx.x;
    int jb = blockIdx.x & 3;
    int chunk = blockIdx.x >> 2;     // 0..63
    int i0 = chunk * 64;

    __shared__ float v[64];
    if (tid < 64) v[tid] = vr[i0 + tid];
    if (tid >= 64 && tid < 80) vz[blockIdx.x * 16 + (tid - 64)] = 0.0f;  // 256*16 = 4096
    __syncthreads();

    int j0 = jb * 1024 + tid * 4;
    float a0 = 0.f, a1 = 0.f, a2 = 0.f, a3 = 0.f;

    if (FP32) {
        const float* base = (const float*)TmV + ((size_t)s << 24) + (size_t)i0 * N + j0;
#pragma unroll 8
        for (int r = 0; r < 64; r++) {
            float4 w = *(const float4*)(base + (size_t)r * N);
            float vi = v[r];
            a0 += vi * w.x;
            a1 += vi * w.y;
            a2 += vi * w.z;
            a3 += vi * w.w;
        }
    } else {
        const unsigned short* base = (const unsigned short*)TmV + ((size_t)s << 24) + (size_t)i0 * N + j0;
#pragma unroll 8
        for (int r = 0; r < 64; r++) {
            uint2 w = *(const uint2*)(base + (size_t)r * N);
            float vi = v[r];
            a0 += vi * bf2f(w.x & 0xffffu);
            a1 += vi * bf2f(w.x >> 16);
            a2 += vi * bf2f(w.y & 0xffffu);
            a3 += vi * bf2f(w.y >> 16);
        }
    }
    atomicAdd(&vw[j0 + 0], a0);
    atomicAdd(&vw[j0 + 1], a1);
    atomicAdd(&vw[j0 + 2], a2);
    atomicAdd(&vw[j0 + 3], a3);

    // fused output projection: out[t] += v_chunk . Om[s][chunk rows]
    if (jb == 0) {
        int r = tid >> 2, c = tid & 3;                     // r: 0..63 rows in chunk
        float p = v[r] * Om[(size_t)s * (N * 4) + (size_t)(i0 + r) * 4 + c];
#pragma unroll
        for (int o = 32; o >= 4; o >>= 1) p += __shfl_down(p, o);
        if ((tid & 63) < 4) atomicAdd(&out[t * 4 + c], p);
    }
}

extern "C" void kernel_launch(void* const* d_in, const int* in_sizes, int n_in,
                              void* d_out, int out_size, void* d_ws, size_t ws_size,
                              hipStream_t stream) {
    const float* sd  = (const float*)d_in[0];   // [4096]
    const int*   seq = (const int*)d_in[1];     // [4096] (int32 or int64 layout)
    const float* T   = (const float*)d_in[2];   // [4096,2,4096]
    const float* O   = (const float*)d_in[3];   // [4096,2,4]
    float* out = (float*)d_out;                 // [4096,4]

    const size_t TM_FP32_BYTES = (size_t)2 * N * N * 4;   // 128 MiB
    const size_t TM_BF16_BYTES = (size_t)2 * N * N * 2;   // 64 MiB
    const size_t OM_BYTES = 2 * N * 4 * sizeof(float);    // 128 KiB
    const size_t BUF_BYTES = 3 * N * sizeof(float);       // 48 KiB
    const size_t SYM_BYTES = L;                           // 4 KiB

    int use_fp32 = (ws_size >= TM_FP32_BYTES + OM_BYTES + BUF_BYTES + SYM_BYTES);
    size_t tm_bytes = use_fp32 ? TM_FP32_BYTES : TM_BF16_BYTES;

    char* ws = (char*)d_ws;
    void* Tm = (void*)ws;
    float* Om   = (float*)(ws + tm_bytes);
    float* bufs = (float*)(ws + tm_bytes + OM_BYTES);
    unsigned char* syms = (unsigned char*)(ws + tm_bytes + OM_BYTES + BUF_BYTES);

    hipLaunchKernelGGL(init_kernel, dim3(64), dim3(256), 0, stream, sd, bufs, out);
    hipLaunchKernelGGL(decode_seq_kernel, dim3(1), dim3(256), 0, stream, seq, syms);
    if (use_fp32) {
        hipLaunchKernelGGL((softmax_T_kernel<1>), dim3(2 * N), dim3(256), 0, stream, T, Tm);
    } else {
        hipLaunchKernelGGL((softmax_T_kernel<0>), dim3(2 * N), dim3(256), 0, stream, T, Tm);
    }
    hipLaunchKernelGGL(softmax_O_kernel, dim3(32), dim3(256), 0, stream, O, Om);

    for (int t = 0; t < L; t++) {
        if (use_fp32) {
            hipLaunchKernelGGL((step_kernel<1>), dim3(256), dim3(256), 0, stream,
                               Tm, Om, syms, bufs, out, t);
        } else {
            hipLaunchKernelGGL((step_kernel<0>), dim3(256), dim3(256), 0, stream,
                               Tm, Om, syms, bufs, out, t);
        }
    }
}